// Round 13
// baseline (44.823 us; speedup 1.0000x reference)
//
#include <hip/hip_runtime.h>
#include <math.h>

#define NF    64      // filters
#define KT    402     // taps: arange(-201, 201)
#define KP    416     // padded taps = 13 * 32
#define NSTEP 13      // K-steps of 32
#define LIN   16000
#define LOUT  15599   // LIN - KT + 1
#define NB    16
#define NT    128     // output positions per block (8 subtiles x 16)
#define SPAN  544     // NT + KP data span per block
#define NCHUNK 68     // SPAN / 8 staging chunks
#define SROW  552     // LDS copy-row stride (elems)
#define CPAD  132     // C-tile row stride (dwords): lane stride 4 banks ->
                      // worst case 2-way conflict on b128 scatter (free)
#define TT    128     // 2 waves per block

typedef __attribute__((ext_vector_type(8))) short short8;   // 8 bf16 (4 VGPR)
typedef __attribute__((ext_vector_type(4))) float f32x4;    // MFMA acc
typedef __attribute__((ext_vector_type(4), aligned(4))) float f32x4u; // 4B-aligned store

// fp32 planes [plane][k][f] for the complex fallback path.
__device__ float g_filt[2 * KT * NF];
// B operand pre-packed in MFMA fragment order: [plane][group][s][lane][j].
// Value = bf16 split of coef(filter = 16*group + (lane&15),
//                            tap    = 8*(lane>>4) + 32*s + j).
__device__ __align__(16) short g_cbf[2][4][NSTEP][64][8];

__device__ __forceinline__ short f2bf(float v) {
    unsigned u = __float_as_uint(v);
    unsigned r = (u + 0x7fffu + ((u >> 16) & 1u)) >> 16;   // RNE
    return (short)r;
}
__device__ __forceinline__ float bf2f(short s) {
    return __uint_as_float(((unsigned)(unsigned short)s) << 16);
}

__global__ void gabor_build_filters(const float* __restrict__ cf,
                                    const float* __restrict__ bw) {
    int idx = blockIdx.x * blockDim.x + threadIdx.x;    // f*KP + k
    if (idx >= NF * KP) return;
    int f = idx / KP;
    int k = idx - f * KP;
    float cre = 0.0f;
    if (k < KT) {
        float t = (float)(k - 201);
        float b = bw[f];
        float env = expf(-(t * t) / (2.0f * b * b)) / (sqrtf(2.0f * (float)M_PI) * b);
        float s, c;
        sincosf(cf[f] * t, &s, &c);
        cre = env * c;
        g_filt[k * NF + f]           = cre;      // re plane (fallback)
        g_filt[KT * NF + k * NF + f] = env * s;  // im plane (fallback)
    }
    short hi = f2bf(cre);
    short lo = f2bf(cre - bf2f(hi));
    // scatter into fragment order: lane = (f&15) | q<<4, with k = 32s + 8q + j
    int g = f >> 4;
    int s = k >> 5;
    int q = (k >> 3) & 3;
    int j = k & 7;
    int l = (f & 15) | (q << 4);
    g_cbf[0][g][s][l][j] = hi;
    g_cbf[1][g][s][l][j] = lo;
}

// MFMA implicit GEMM, real part only. R8's K-loop verbatim (fully unrolled,
// B at use) + R12's coalesced LDS-transpose epilogue, now in TWO half-tile
// passes (32 rows x CPAD = 16.9 KB) so the union stays within the 17.7 KB
// A-buffer -> LDS 17.7 KB -> 8 blocks/CU (R12 post-mortem: the full C-tile
// union doubled LDS, halved occupancy to ~1.4 waves/SIMD, and the K-loop's
// at-use B loads (L2 ~250cyc x 13 steps) became latency-exposed; the clean
// stores were exactly cancelled). launch_bounds(128,4) targets 4 waves/SIMD.
// A (Hankel of x) from LDS via 8 shifted bf16 copies (copy c holds elem i at
// index i-c -> every fragment one aligned ds_read_b128).
// 3-term bf16 split (Ah*Bh + Al*Bh + Ah*Bl) emulates fp32.
__global__ __launch_bounds__(TT, 4) void gabor_conv_mfma(const float* __restrict__ x,
                                                         float* __restrict__ out,
                                                         long out_elems) {
    __shared__ __align__(16) union {
        struct { short h[8][SROW]; short l[8][SROW]; } a;  // 17,664 B
        float c[32][CPAD];                                 // 16,896 B (half tile)
    } sm;

    const int tile = blockIdx.x;
    const int b    = blockIdx.y;
    const int n0   = tile * NT;
    const int tid  = threadIdx.x;
    const int wid  = tid >> 6;      // 0..1
    const int lane = tid & 63;

    // ---- Vectorized staging: thread j < 68 owns x elements [8j, 8j+16),
    // builds all 8 shifted windows in registers, writes 16 ds_write_b128.
    if (tid < NCHUNK) {
        const int j  = tid;
        const int e0 = 8 * j;
        const float* __restrict__ src = x + (size_t)b * LIN + n0 + e0;

        float xv[16];
        if (n0 + e0 + 16 <= LIN) {
#pragma unroll
            for (int q = 0; q < 4; ++q) {
                float4 v = *reinterpret_cast<const float4*>(src + 4 * q);
                xv[4 * q + 0] = v.x; xv[4 * q + 1] = v.y;
                xv[4 * q + 2] = v.z; xv[4 * q + 3] = v.w;
            }
        } else {
#pragma unroll
            for (int i = 0; i < 16; ++i) {
                int gi = n0 + e0 + i;
                xv[i] = (gi < LIN) ? src[i] : 0.0f;
            }
        }

        unsigned hd[8], ld[8];   // packed bf16 pairs (low16 = even elem)
#pragma unroll
        for (int i = 0; i < 8; ++i) {
            unsigned h0 = (unsigned short)f2bf(xv[2 * i]);
            unsigned h1 = (unsigned short)f2bf(xv[2 * i + 1]);
            hd[i] = h0 | (h1 << 16);
            unsigned l0 = (unsigned short)f2bf(xv[2 * i]     - bf2f((short)h0));
            unsigned l1 = (unsigned short)f2bf(xv[2 * i + 1] - bf2f((short)h1));
            ld[i] = l0 | (l1 << 16);
        }

#pragma unroll
        for (int c = 0; c < 8; ++c) {
            unsigned wh[4], wl[4];
            if ((c & 1) == 0) {
#pragma unroll
                for (int i = 0; i < 4; ++i) {
                    wh[i] = hd[c / 2 + i];
                    wl[i] = ld[c / 2 + i];
                }
            } else {
#pragma unroll
                for (int i = 0; i < 4; ++i) {
                    int k2 = (c - 1) / 2 + i;
                    wh[i] = (hd[k2] >> 16) | (hd[k2 + 1] << 16);   // v_alignbit
                    wl[i] = (ld[k2] >> 16) | (ld[k2 + 1] << 16);
                }
            }
            uint4 vh = {wh[0], wh[1], wh[2], wh[3]};
            uint4 vl = {wl[0], wl[1], wl[2], wl[3]};
            *reinterpret_cast<uint4*>(&sm.a.h[c][e0]) = vh;
            *reinterpret_cast<uint4*>(&sm.a.l[c][e0]) = vl;
        }
    }
    __syncthreads();

    // ---- MFMA phase (R8 verbatim)
    const int c8    = lane & 7;
    const int abase = 8 * ((lane >> 3) & 1) + 8 * (lane >> 4);
    const short* ah_base = &sm.a.h[c8][abase];
    const short* al_base = &sm.a.l[c8][abase];
    const int subbase = wid * 4;    // this wave's first position-subtile

    f32x4 acc[4][4];                // [n][group], all-static indexing
#pragma unroll
    for (int n = 0; n < 4; ++n)
#pragma unroll
        for (int g = 0; g < 4; ++g) {
            f32x4 z = {0.0f, 0.0f, 0.0f, 0.0f};
            acc[n][g] = z;
        }

#pragma unroll
    for (int s = 0; s < NSTEP; ++s) {
        short8 bh[4], bl[4];
#pragma unroll
        for (int g = 0; g < 4; ++g) {
            bh[g] = *(const short8*)(&g_cbf[0][g][s][lane][0]);
            bl[g] = *(const short8*)(&g_cbf[1][g][s][lane][0]);
        }
#pragma unroll
        for (int n = 0; n < 4; ++n) {
            const int m = subbase + n + 2 * s;
            short8 ah = *(const short8*)(ah_base + 16 * m);
            short8 al = *(const short8*)(al_base + 16 * m);
#pragma unroll
            for (int g = 0; g < 4; ++g) {
                acc[n][g] = __builtin_amdgcn_mfma_f32_16x16x32_bf16(ah, bh[g], acc[n][g], 0, 0, 0);
                acc[n][g] = __builtin_amdgcn_mfma_f32_16x16x32_bf16(al, bh[g], acc[n][g], 0, 0, 0);
                acc[n][g] = __builtin_amdgcn_mfma_f32_16x16x32_bf16(ah, bl[g], acc[n][g], 0, 0, 0);
            }
        }
    }

    // ---- Epilogue: two half-tile LDS-transpose passes -> coalesced stores.
    const int colr  = 4 * (lane & 31);
    const int rhalf = lane >> 5;    // 0..1
    __syncthreads();    // all waves done reading sm.a before scatter clobbers it

#pragma unroll
    for (int half = 0; half < 2; ++half) {
        // Scatter groups 2*half, 2*half+1: D col = lane&15 = filter-in-group,
        // rows 4*(lane>>4)+r = 4 consecutive positions -> aligned b128 write.
#pragma unroll
        for (int n = 0; n < 4; ++n) {
            const int colbase = 16 * (subbase + n) + 4 * (lane >> 4);
#pragma unroll
            for (int gg = 0; gg < 2; ++gg) {
                const int row = 16 * gg + (lane & 15);   // row within half-tile
                *reinterpret_cast<f32x4*>(&sm.c[row][colbase]) = acc[n][2 * half + gg];
            }
        }
        __syncthreads();

        // Stream out: 2 rows x 32 lanes x dwordx4 = 512 B contiguous per row.
        // Wave w handles local rows 16w..16w+15.
#pragma unroll
        for (int rr = 0; rr < 8; ++rr) {
            const int rloc = 16 * wid + 2 * rr + rhalf;  // 0..31
            const int f    = 32 * half + rloc;           // filter index
            const int np   = n0 + colr;
            const size_t o = (size_t)(b * NF + f) * LOUT + np;
            f32x4 v = *reinterpret_cast<const f32x4*>(&sm.c[rloc][colr]);
            if (np + 3 < LOUT && (long)(o + 3) < out_elems) {
                *reinterpret_cast<f32x4u*>(out + o) = v;
            } else {
#pragma unroll
                for (int r = 0; r < 4; ++r)
                    if (np + r < LOUT && (long)(o + r) < out_elems)
                        out[o + r] = v[r];
            }
        }
        if (half == 0) __syncthreads();   // before next scatter clobbers sm.c
    }
}

// Complex fallback (folded fp32) in case d_out is interleaved complex.
__global__ __launch_bounds__(256) void gabor_conv_cplx(const float* __restrict__ x,
                                                       float* __restrict__ out,
                                                       long out_elems) {
    __shared__ float sx[256 + KT];
    const int tile = blockIdx.x, g = blockIdx.y, b = blockIdx.z;
    const int t0 = tile * 256, tid = threadIdx.x;
    const float* __restrict__ xb = x + (size_t)b * LIN;
    for (int i = tid; i < 256 + KT - 1; i += 256) {
        int idx = t0 + i;
        sx[i] = (idx < LIN) ? xb[idx] : 0.0f;
    }
    __syncthreads();
    const float* fre = g_filt + g * 16;
    const float* fim = g_filt + KT * NF + g * 16;
    float accre[16], accim[16];
    {
        float x0 = sx[tid], xm = sx[tid + 201];
        const float* c0 = fre;
        const float* cm = fre + 201 * NF;
#pragma unroll
        for (int j = 0; j < 16; ++j) accre[j] = __builtin_fmaf(xm, cm[j], x0 * c0[j]);
#pragma unroll
        for (int j = 0; j < 16; ++j) accim[j] = x0 * fim[j];
    }
#pragma unroll 2
    for (int p = 1; p <= 200; ++p) {
        float x1 = sx[tid + p], x2 = sx[tid + 402 - p];
        float xs = x1 + x2, xd = x1 - x2;
        const float* cr = fre + p * NF;
        const float* ci = fim + p * NF;
#pragma unroll
        for (int j = 0; j < 16; ++j) accre[j] = __builtin_fmaf(xs, cr[j], accre[j]);
#pragma unroll
        for (int j = 0; j < 16; ++j) accim[j] = __builtin_fmaf(xd, ci[j], accim[j]);
    }
    const int t = t0 + tid;
    if (t < LOUT) {
#pragma unroll
        for (int j = 0; j < 16; ++j) {
            size_t o = ((size_t)(b * NF + g * 16 + j) * LOUT + t) * 2;
            if ((long)(o + 1) < out_elems) {
                float2 v; v.x = accre[j]; v.y = accim[j];
                *reinterpret_cast<float2*>(out + o) = v;
            }
        }
    }
}

extern "C" void kernel_launch(void* const* d_in, const int* in_sizes, int n_in,
                              void* d_out, int out_size, void* d_ws, size_t ws_size,
                              hipStream_t stream) {
    const float* x  = (const float*)d_in[0];
    const float* cf = (const float*)d_in[1];
    const float* bw = (const float*)d_in[2];
    float* out = (float*)d_out;
    (void)d_ws; (void)ws_size;

    {
        int n = NF * KP;
        gabor_build_filters<<<(n + 255) / 256, 256, 0, stream>>>(cf, bw);
    }

    const long n_complex = (long)NB * NF * LOUT;
    const bool cplx = ((long)out_size >= 2 * n_complex);

    if (cplx) {
        dim3 grid((LOUT + 255) / 256, NF / 16, NB);
        gabor_conv_cplx<<<grid, 256, 0, stream>>>(x, out, (long)out_size);
    } else {
        dim3 grid((LOUT + NT - 1) / NT, NB);   // (122, 16)
        gabor_conv_mfma<<<grid, TT, 0, stream>>>(x, out, (long)out_size);
    }
}

// Round 14
// 41.863 us; speedup vs baseline: 1.0707x; 1.0707x over previous
//
#include <hip/hip_runtime.h>
#include <math.h>

#define NF    64      // filters
#define KT    402     // taps: arange(-201, 201)
#define KP    416     // padded taps = 13 * 32
#define NSTEP 13      // K-steps of 32
#define LIN   16000
#define LOUT  15599   // LIN - KT + 1
#define NB    16
#define NT    256     // output positions per block (16 subtiles x 16)
#define SPAN  672     // NT + KP data span per block
#define NCHUNK 84     // SPAN / 8 staging chunks
#define SROW  680     // A copy-row stride (elems)
#define CPAD  260     // C-tile row stride (dwords); 260 mod 32 = 4
#define TT    256     // 4 waves per block

typedef __attribute__((ext_vector_type(8))) short short8;   // 8 bf16 (4 VGPR)
typedef __attribute__((ext_vector_type(4))) float f32x4;    // MFMA acc
typedef __attribute__((ext_vector_type(4), aligned(4))) float f32x4u; // 4B-aligned store

// fp32 planes [plane][k][f] for the complex fallback path.
__device__ float g_filt[2 * KT * NF];
// B operand pre-packed in MFMA fragment order: [plane][group][s][lane][j].
// Value = bf16 split of coef(filter = 16*group + (lane&15),
//                            tap    = 8*(lane>>4) + 32*s + j).
// Each [plane][group][s] slice is 1 KB contiguous -> one gll16 per wave.
__device__ __align__(16) short g_cbf[2][4][NSTEP][64][8];

__device__ __forceinline__ short f2bf(float v) {
    unsigned u = __float_as_uint(v);
    unsigned r = (u + 0x7fffu + ((u >> 16) & 1u)) >> 16;   // RNE
    return (short)r;
}
__device__ __forceinline__ float bf2f(short s) {
    return __uint_as_float(((unsigned)(unsigned short)s) << 16);
}
// Async global->LDS 16B: per-lane global src, wave-uniform LDS base (+lane*16).
__device__ __forceinline__ void gll16(const void* g, void* l) {
    __builtin_amdgcn_global_load_lds(
        (const __attribute__((address_space(1))) void*)g,
        (__attribute__((address_space(3))) void*)l, 16, 0, 0);
}

__global__ void gabor_build_filters(const float* __restrict__ cf,
                                    const float* __restrict__ bw) {
    int idx = blockIdx.x * blockDim.x + threadIdx.x;    // f*KP + k
    if (idx >= NF * KP) return;
    int f = idx / KP;
    int k = idx - f * KP;
    float cre = 0.0f;
    if (k < KT) {
        float t = (float)(k - 201);
        float b = bw[f];
        float env = expf(-(t * t) / (2.0f * b * b)) / (sqrtf(2.0f * (float)M_PI) * b);
        float s, c;
        sincosf(cf[f] * t, &s, &c);
        cre = env * c;
        g_filt[k * NF + f]           = cre;      // re plane (fallback)
        g_filt[KT * NF + k * NF + f] = env * s;  // im plane (fallback)
    }
    short hi = f2bf(cre);
    short lo = f2bf(cre - bf2f(hi));
    int g = f >> 4;
    int s = k >> 5;
    int q = (k >> 3) & 3;
    int j = k & 7;
    int l = (f & 15) | (q << 4);
    g_cbf[0][g][s][l][j] = hi;
    g_cbf[1][g][s][l][j] = lo;
}

// MFMA implicit GEMM, real part only. T3 minimum-2-phase K-loop:
// per step, issue next step's B stage (global_load_lds into LDS dbuf) FIRST,
// then ds_read current B+A, 48 MFMAs (latency cover), then
// asm vmcnt(0) + RAW s_barrier + sched_barrier(0) -- no __syncthreads drain
// before the MFMA cluster (R11's failure mode). B is shared by 4 waves ->
// per-wave L2 B traffic drops 4x vs R8/R13's at-use register loads
// (R13 post-mortem: occupancy recovered but time flat -> B path is binding).
// A (Hankel of x) via 8 shifted bf16 copies, one aligned ds_read_b128/frag.
// 3-term bf16 split (Ah*Bh + Al*Bh + Ah*Bl) emulates fp32.
__global__ __launch_bounds__(TT, 3) void gabor_conv_mfma(const float* __restrict__ x,
                                                         float* __restrict__ out,
                                                         long out_elems) {
    __shared__ __align__(16) union {
        struct {
            short h[8][SROW];          // 10,880 B
            short l[8][SROW];          // 10,880 B
            short bb[2][8][64][8];     // 16,384 B  [buf][region][lane][j]
        } k;                           // 38,144 B
        float c[32][CPAD];             // 33,280 B (half C-tile)
    } sm;

    const int tile = blockIdx.x;
    const int b    = blockIdx.y;
    const int n0   = tile * NT;
    const int tid  = threadIdx.x;
    const int wid  = tid >> 6;      // 0..3
    const int lane = tid & 63;

    // Prologue: stage B step 0 (wave w -> regions w, 4+w; 1 KB each).
    gll16(&g_cbf[0][wid][0][lane][0], &sm.k.bb[0][wid][0][0]);
    gll16(&g_cbf[1][wid][0][lane][0], &sm.k.bb[0][4 + wid][0][0]);

    // ---- Vectorized A staging: thread j < 84 owns x elements [8j, 8j+16),
    // builds all 8 shifted windows in registers, writes 16 ds_write_b128.
    if (tid < NCHUNK) {
        const int j  = tid;
        const int e0 = 8 * j;
        const float* __restrict__ src = x + (size_t)b * LIN + n0 + e0;

        float xv[16];
        if (n0 + e0 + 16 <= LIN) {
#pragma unroll
            for (int q = 0; q < 4; ++q) {
                float4 v = *reinterpret_cast<const float4*>(src + 4 * q);
                xv[4 * q + 0] = v.x; xv[4 * q + 1] = v.y;
                xv[4 * q + 2] = v.z; xv[4 * q + 3] = v.w;
            }
        } else {
#pragma unroll
            for (int i = 0; i < 16; ++i) {
                int gi = n0 + e0 + i;
                xv[i] = (gi < LIN) ? src[i] : 0.0f;
            }
        }

        unsigned hd[8], ld[8];   // packed bf16 pairs (low16 = even elem)
#pragma unroll
        for (int i = 0; i < 8; ++i) {
            unsigned h0 = (unsigned short)f2bf(xv[2 * i]);
            unsigned h1 = (unsigned short)f2bf(xv[2 * i + 1]);
            hd[i] = h0 | (h1 << 16);
            unsigned l0 = (unsigned short)f2bf(xv[2 * i]     - bf2f((short)h0));
            unsigned l1 = (unsigned short)f2bf(xv[2 * i + 1] - bf2f((short)h1));
            ld[i] = l0 | (l1 << 16);
        }

#pragma unroll
        for (int c = 0; c < 8; ++c) {
            unsigned wh[4], wl[4];
            if ((c & 1) == 0) {
#pragma unroll
                for (int i = 0; i < 4; ++i) {
                    wh[i] = hd[c / 2 + i];
                    wl[i] = ld[c / 2 + i];
                }
            } else {
#pragma unroll
                for (int i = 0; i < 4; ++i) {
                    int k2 = (c - 1) / 2 + i;
                    wh[i] = (hd[k2] >> 16) | (hd[k2 + 1] << 16);   // v_alignbit
                    wl[i] = (ld[k2] >> 16) | (ld[k2 + 1] << 16);
                }
            }
            uint4 vh = {wh[0], wh[1], wh[2], wh[3]};
            uint4 vl = {wl[0], wl[1], wl[2], wl[3]};
            *reinterpret_cast<uint4*>(&sm.k.h[c][e0]) = vh;
            *reinterpret_cast<uint4*>(&sm.k.l[c][e0]) = vl;
        }
    }
    __syncthreads();    // full drain: A ds_writes + B0 stage landed

    // ---- Phased K-loop
    const int c8    = lane & 7;
    const int abase = 8 * ((lane >> 3) & 1) + 8 * (lane >> 4);
    const int subbase = wid * 4;    // this wave's first position-subtile
    const short* ah_base = &sm.k.h[c8][abase + 16 * subbase];
    const short* al_base = &sm.k.l[c8][abase + 16 * subbase];

    f32x4 acc[4][4];                // [n][group], all-static indexing
#pragma unroll
    for (int n = 0; n < 4; ++n)
#pragma unroll
        for (int g = 0; g < 4; ++g) {
            f32x4 z = {0.0f, 0.0f, 0.0f, 0.0f};
            acc[n][g] = z;
        }

#pragma unroll
    for (int s = 0; s < NSTEP; ++s) {
        const int cur = s & 1;
        // Issue next step's stage first (latency hides under this step's MFMAs).
        if (s + 1 < NSTEP) {
            gll16(&g_cbf[0][wid][s + 1][lane][0], &sm.k.bb[cur ^ 1][wid][0][0]);
            gll16(&g_cbf[1][wid][s + 1][lane][0], &sm.k.bb[cur ^ 1][4 + wid][0][0]);
        }
        // Current B from LDS (staged last step; validity: prev phase's
        // vmcnt(0)+barrier; first step: the __syncthreads above).
        short8 bh[4], bl[4];
#pragma unroll
        for (int g = 0; g < 4; ++g) {
            bh[g] = *(const short8*)(&sm.k.bb[cur][g][lane][0]);
            bl[g] = *(const short8*)(&sm.k.bb[cur][4 + g][lane][0]);
        }
        __builtin_amdgcn_s_setprio(1);
#pragma unroll
        for (int n = 0; n < 4; ++n) {
            short8 ah = *(const short8*)(ah_base + 16 * n + 32 * s);
            short8 al = *(const short8*)(al_base + 16 * n + 32 * s);
#pragma unroll
            for (int g = 0; g < 4; ++g) {
                acc[n][g] = __builtin_amdgcn_mfma_f32_16x16x32_bf16(ah, bh[g], acc[n][g], 0, 0, 0);
                acc[n][g] = __builtin_amdgcn_mfma_f32_16x16x32_bf16(al, bh[g], acc[n][g], 0, 0, 0);
                acc[n][g] = __builtin_amdgcn_mfma_f32_16x16x32_bf16(ah, bl[g], acc[n][g], 0, 0, 0);
            }
        }
        __builtin_amdgcn_s_setprio(0);
        // Phase close: own stage landed; all waves aligned; no reordering.
        asm volatile("s_waitcnt vmcnt(0)" ::: "memory");
        __builtin_amdgcn_s_barrier();
        __builtin_amdgcn_sched_barrier(0);
    }

    // ---- Epilogue: two half-tile LDS-transpose passes -> coalesced stores.
    __syncthreads();    // before scatter clobbers the k-region via union

#pragma unroll
    for (int half = 0; half < 2; ++half) {
#pragma unroll
        for (int n = 0; n < 4; ++n) {
            const int colbase = 16 * (subbase + n) + 4 * (lane >> 4);
#pragma unroll
            for (int gg = 0; gg < 2; ++gg) {
                const int row = 16 * gg + (lane & 15);   // row within half-tile
                *reinterpret_cast<f32x4*>(&sm.c[row][colbase]) = acc[n][2 * half + gg];
            }
        }
        __syncthreads();

        // Stream out: one full 256-pos row per wave-instruction (1024 B).
#pragma unroll
        for (int rr = 0; rr < 8; ++rr) {
            const int rloc = 8 * wid + rr;               // 0..31
            const int f    = 32 * half + rloc;           // filter index
            const int np   = n0 + 4 * lane;
            const size_t o = (size_t)(b * NF + f) * LOUT + np;
            f32x4 v = *reinterpret_cast<const f32x4*>(&sm.c[rloc][4 * lane]);
            if (np + 3 < LOUT && (long)(o + 3) < out_elems) {
                *reinterpret_cast<f32x4u*>(out + o) = v;
            } else {
#pragma unroll
                for (int r = 0; r < 4; ++r)
                    if (np + r < LOUT && (long)(o + r) < out_elems)
                        out[o + r] = v[r];
            }
        }
        if (half == 0) __syncthreads();   // before next scatter clobbers sm.c
    }
}

// Complex fallback (folded fp32) in case d_out is interleaved complex.
__global__ __launch_bounds__(256) void gabor_conv_cplx(const float* __restrict__ x,
                                                       float* __restrict__ out,
                                                       long out_elems) {
    __shared__ float sx[256 + KT];
    const int tile = blockIdx.x, g = blockIdx.y, b = blockIdx.z;
    const int t0 = tile * 256, tid = threadIdx.x;
    const float* __restrict__ xb = x + (size_t)b * LIN;
    for (int i = tid; i < 256 + KT - 1; i += 256) {
        int idx = t0 + i;
        sx[i] = (idx < LIN) ? xb[idx] : 0.0f;
    }
    __syncthreads();
    const float* fre = g_filt + g * 16;
    const float* fim = g_filt + KT * NF + g * 16;
    float accre[16], accim[16];
    {
        float x0 = sx[tid], xm = sx[tid + 201];
        const float* c0 = fre;
        const float* cm = fre + 201 * NF;
#pragma unroll
        for (int j = 0; j < 16; ++j) accre[j] = __builtin_fmaf(xm, cm[j], x0 * c0[j]);
#pragma unroll
        for (int j = 0; j < 16; ++j) accim[j] = x0 * fim[j];
    }
#pragma unroll 2
    for (int p = 1; p <= 200; ++p) {
        float x1 = sx[tid + p], x2 = sx[tid + 402 - p];
        float xs = x1 + x2, xd = x1 - x2;
        const float* cr = fre + p * NF;
        const float* ci = fim + p * NF;
#pragma unroll
        for (int j = 0; j < 16; ++j) accre[j] = __builtin_fmaf(xs, cr[j], accre[j]);
#pragma unroll
        for (int j = 0; j < 16; ++j) accim[j] = __builtin_fmaf(xd, ci[j], accim[j]);
    }
    const int t = t0 + tid;
    if (t < LOUT) {
#pragma unroll
        for (int j = 0; j < 16; ++j) {
            size_t o = ((size_t)(b * NF + g * 16 + j) * LOUT + t) * 2;
            if ((long)(o + 1) < out_elems) {
                float2 v; v.x = accre[j]; v.y = accim[j];
                *reinterpret_cast<float2*>(out + o) = v;
            }
        }
    }
}

extern "C" void kernel_launch(void* const* d_in, const int* in_sizes, int n_in,
                              void* d_out, int out_size, void* d_ws, size_t ws_size,
                              hipStream_t stream) {
    const float* x  = (const float*)d_in[0];
    const float* cf = (const float*)d_in[1];
    const float* bw = (const float*)d_in[2];
    float* out = (float*)d_out;
    (void)d_ws; (void)ws_size;

    {
        int n = NF * KP;
        gabor_build_filters<<<(n + 255) / 256, 256, 0, stream>>>(cf, bw);
    }

    const long n_complex = (long)NB * NF * LOUT;
    const bool cplx = ((long)out_size >= 2 * n_complex);

    if (cplx) {
        dim3 grid((LOUT + 255) / 256, NF / 16, NB);
        gabor_conv_cplx<<<grid, 256, 0, stream>>>(x, out, (long)out_size);
    } else {
        dim3 grid((LOUT + NT - 1) / NT, NB);   // (61, 16)
        gabor_conv_mfma<<<grid, TT, 0, stream>>>(x, out, (long)out_size);
    }
}